// Round 15
// baseline (4046.969 us; speedup 1.0000x reference)
//
#include <hip/hip_runtime.h>
#include <cmath>

// Sinkhorn distance, B=8, P1=P2=2048, dim=3, EPS=1, MAX_ITER=100, THRESH=1e-9
// Outputs (flat, in return order): cost[8], pi[8*2048*2048], D[8*2048*2048]
//
// Identities / hard-won rules:
//  - log2 domain everywhere; coords pre-scaled by log2(e); duals log2-space;
//    weights log2(1/2048) = -11.  u'_i = -11 - log2( sum_j exp2(v'_j) E_ij )
//  - E_ij = exp2(-d'_ij) is CONSTANT across iterations: precompute once in
//    fp16 (RTN -> unbiased quantization, errors cancel in the positive sum),
//    plus E^T for the v-phase (coalesced row-slices). E+E^T = 134 MB lives
//    in the pi OUTPUT region (unused until sk_final overwrites it; sk_final
//    never reads E). 134 MB is Infinity-Cache resident.
//  - Each phase = GEMV: uint4 loads of 8 fp16 E-entries + v_dot2_f32_f16.
//  - THRESH=1e-9 < f32 ulp => reference runs all 100 iters (R8 measured).
//  - Cross-wg dual exchange: 32-BIT agent-scope RELAXED atomics only
//    (64-bit atomic loads lower to RMW -> 10 GB HBM, R9). NO fences (R6).
//  - Barrier: arrival fetch_add on write-only counter; 64th arriver stores a
//    separate once-written release flag everyone polls (one hot line/batch).
//  - Register budget 64 VGPRs (launch_bounds 1024,8): keep live arrays tiny
//    (R12: spill -> 59 GB HBM, 7x slowdown).
//  - Final D/pi/cost in a separate 16384-block kernel (R13: folding cost +290us).

constexpr int BATCH = 8;
constexpr int P = 2048;
constexpr int MAX_ITER = 100;
constexpr int WGS_PER_BATCH = 64;            // 32 rows each
constexpr int NWG = BATCH * WGS_PER_BATCH;   // 512 blocks
constexpr int TPB = 1024;                    // 16 waves
constexpr int NPHASE = 2 * MAX_ITER;

#define LOG2E 1.44269504088896340736f
#define LN2   0.69314718055994530942f

typedef __attribute__((ext_vector_type(2))) _Float16 h2f;

static __device__ __forceinline__ float dot2acc(unsigned e_bits, h2f w2, float acc)
{
    h2f e2 = __builtin_bit_cast(h2f, e_bits);
#if __has_builtin(__builtin_amdgcn_fdot2)
    return __builtin_amdgcn_fdot2(e2, w2, acc, false);
#else
    return acc + (float)e2.x * (float)w2.x + (float)e2.y * (float)w2.y;
#endif
}

// Pack pre-scaled coords into float4; init duals; zero counters + release flags.
__global__ __launch_bounds__(256) void sk_prep(const float* __restrict__ x,
                                               const float* __restrict__ y,
                                               float4* __restrict__ xs,
                                               float4* __restrict__ ys,
                                               float* __restrict__ u,
                                               float* __restrict__ v,
                                               int* __restrict__ cnt)
{
    int idx = blockIdx.x * 256 + threadIdx.x;   // 0 .. BATCH*P-1
    u[idx] = 0.0f;     // log2-space u0 = 0
    v[idx] = -11.0f;   // log2-space v0 = log2(1/2048)
    xs[idx] = make_float4(LOG2E * x[3*idx], LOG2E * x[3*idx+1], LOG2E * x[3*idx+2], 0.f);
    ys[idx] = make_float4(LOG2E * y[3*idx], LOG2E * y[3*idx+1], LOG2E * y[3*idx+2], 0.f);
    if (idx < 2 * BATCH * NPHASE) cnt[idx] = 0;   // arrivals + release flags
}

// Precompute E (x-rows) and E^T (y-rows) in fp16 (RTN). One block per row.
__global__ __launch_bounds__(256) void sk_einit(const float4* __restrict__ xs,
                                                const float4* __restrict__ ys,
                                                uint4* __restrict__ E,
                                                uint4* __restrict__ ET)
{
    const int nrows = BATCH * P;
    const int id = blockIdx.x;
    const bool yside = id >= nrows;
    const int row = yside ? id - nrows : id;    // b*P + r
    const int b = row >> 11;
    const float4 a = yside ? ys[row] : xs[row];
    const float4* other = (yside ? xs : ys) + (size_t)b * P;
    uint4* dst = (yside ? ET : E) + (size_t)row * (P / 8);

    const int j0 = threadIdx.x * 8;             // 8 consecutive j per thread
    unsigned dw[4];
    #pragma unroll
    for (int p = 0; p < 4; ++p) {
        float4 q0 = other[j0 + 2*p];
        float4 q1 = other[j0 + 2*p + 1];
        h2f hh;
        {
            float dx = a.x - q0.x, dy = a.y - q0.y, dz = a.z - q0.z;
            float ds = __builtin_amdgcn_sqrtf(fmaf(dx, dx, fmaf(dy, dy, dz * dz)));
            hh.x = (_Float16)__builtin_amdgcn_exp2f(-ds);   // RTN cvt
        }
        {
            float dx = a.x - q1.x, dy = a.y - q1.y, dz = a.z - q1.z;
            float ds = __builtin_amdgcn_sqrtf(fmaf(dx, dx, fmaf(dy, dy, dz * dz)));
            hh.y = (_Float16)__builtin_amdgcn_exp2f(-ds);
        }
        dw[p] = __builtin_bit_cast(unsigned, hh);
    }
    dst[threadIdx.x] = make_uint4(dw[0], dw[1], dw[2], dw[3]);
}

// The Sinkhorn loop as per-phase GEMV against fp16 E / E^T.
// Block: 1024 thr = 16 waves = 8 row-quads x 2 j-halves; 32 output rows/wg.
__global__ __launch_bounds__(TPB, 8) void sk_loop(const uint4* __restrict__ E,
                                                  const uint4* __restrict__ ET,
                                                  float* u,
                                                  float* v,
                                                  int* cnt)
{
    __shared__ float wpart[16][4];

    const int b = blockIdx.x & 7;                   // batch (XCD-local heuristic)
    const int wg = blockIdx.x >> 3;                 // 0..63 within batch
    const int wgrow = wg << 5;                      // this wg's 32-row base
    const int w = threadIdx.x >> 6;
    const int lane = threadIdx.x & 63;
    const int quad = w & 7;                         // row-quad 0..7
    const int half = w >> 3;                        // j half-range
    const int i0 = wgrow + quad * 4;

    float* ub = u + (size_t)b * P;
    float* vb = v + (size_t)b * P;
    int* bar = cnt + b * NPHASE;                    // arrival counters (write-only)
    int* rel = cnt + BATCH * NPHASE + b * NPHASE;   // release flags (single writer)

    #pragma unroll 1
    for (int it = 0; it < MAX_ITER; ++it) {
        #pragma unroll 1
        for (int ph = 0; ph < 2; ++ph) {
            float* dr = ph ? ub : vb;               // duals being reduced over
            float* dw = ph ? vb : ub;               // duals being written
            const uint4* M = ph ? ET : E;           // matrix with output rows as rows

            // Preload this wave's 16 duals (32-bit sc1 loads), exp2, pack fp16.
            float dd[16];
            #pragma unroll
            for (int k = 0; k < 2; ++k) {
                const int fj = ((half << 7) + lane + (k << 6)) << 3;  // 8 consecutive floats
                #pragma unroll
                for (int m = 0; m < 8; ++m)
                    dd[k*8 + m] = __hip_atomic_load(&dr[fj + m], __ATOMIC_RELAXED,
                                                    __HIP_MEMORY_SCOPE_AGENT);
            }
            h2f W[2][4];
            #pragma unroll
            for (int k = 0; k < 2; ++k)
                #pragma unroll
                for (int p = 0; p < 4; ++p) {
                    h2f hh;
                    hh.x = (_Float16)__builtin_amdgcn_exp2f(dd[k*8 + 2*p]);     // RTN
                    hh.y = (_Float16)__builtin_amdgcn_exp2f(dd[k*8 + 2*p + 1]);
                    W[k][p] = hh;
                }

            const size_t rowbase4 = (size_t)(b * P + i0) * (P / 8);
            float acc[4] = {0.f, 0.f, 0.f, 0.f};

            #pragma unroll
            for (int k = 0; k < 2; ++k) {
                const int t4 = (half << 7) + lane + (k << 6);   // uint4 index in row
                #pragma unroll
                for (int r = 0; r < 4; ++r) {
                    uint4 ev = M[rowbase4 + (size_t)r * (P / 8) + t4];
                    acc[r] = dot2acc(ev.x, W[k][0], acc[r]);
                    acc[r] = dot2acc(ev.y, W[k][1], acc[r]);
                    acc[r] = dot2acc(ev.z, W[k][2], acc[r]);
                    acc[r] = dot2acc(ev.w, W[k][3], acc[r]);
                }
            }

            #pragma unroll
            for (int r = 0; r < 4; ++r) {
                float s = acc[r];
                #pragma unroll
                for (int off = 32; off; off >>= 1) s += __shfl_xor(s, off);
                if (lane == 0) wpart[w][r] = s;
            }
            __syncthreads();

            // combine j-halves; write this wg's 32 duals via sc1 stores (wave 0)
            if (threadIdx.x < 32) {
                const int q = threadIdx.x >> 2;
                const int r = threadIdx.x & 3;
                float s = wpart[q][r] + wpart[q + 8][r];
                float val = -11.0f - __builtin_amdgcn_logf(s);
                __hip_atomic_store(&dw[wgrow + threadIdx.x], val,
                                   __ATOMIC_RELAXED, __HIP_MEMORY_SCOPE_AGENT);
            }

            // Per-batch barrier, arrival/release split. Skip after last phase
            // (kernel boundary syncs before sk_final).
            if (it == MAX_ITER - 1 && ph == 1) continue;
            if (threadIdx.x == 0) {
                const int idx = it * 2 + ph;
                asm volatile("s_waitcnt vmcnt(0)" ::: "memory");  // duals acked at IF
                int old = __hip_atomic_fetch_add(&bar[idx], 1, __ATOMIC_RELAXED,
                                                 __HIP_MEMORY_SCOPE_AGENT);
                if (old == WGS_PER_BATCH - 1) {
                    __hip_atomic_store(&rel[idx], 1, __ATOMIC_RELAXED,
                                       __HIP_MEMORY_SCOPE_AGENT);
                } else {
                    while (__hip_atomic_load(&rel[idx], __ATOMIC_RELAXED,
                                             __HIP_MEMORY_SCOPE_AGENT) == 0)
                        __builtin_amdgcn_s_sleep(2);
                }
            }
            __syncthreads();
        }
    }
}

// Final: D, pi = exp(D + u + v) (faithful to reference's +D sign), rowsum of pi*D.
// One block per output row; float4 loads/stores. Overwrites the E storage (never
// read here) with the real pi output.
__global__ __launch_bounds__(256) void sk_final(const float4* __restrict__ xs,
                                                const float4* __restrict__ ys,
                                                const float* __restrict__ u,
                                                const float* __restrict__ v,
                                                float4* __restrict__ outPi,
                                                float4* __restrict__ outD,
                                                float* __restrict__ rowsum)
{
    const int row = blockIdx.x;        // b*P + i
    const int b = row >> 11;

    const float4 a = xs[row];          // scaled x_i
    const float u2 = u[row];           // log2-space u_i
    const float4* vb4 = (const float4*)(v + (size_t)b * P);
    const float4* yb = ys + (size_t)b * P;
    const size_t base4 = (size_t)row * (P / 4);

    float acc = 0.f;
    for (int t = threadIdx.x; t < P / 4; t += 256) {
        float4 dv, pv;
        float4 vv = vb4[t];
        #pragma unroll
        for (int c = 0; c < 4; ++c) {
            int j = 4 * t + c;
            float4 q = yb[j];
            float dx = a.x - q.x;
            float dy = a.y - q.y;
            float dz = a.z - q.z;
            float ds = __builtin_amdgcn_sqrtf(fmaf(dx, dx, fmaf(dy, dy, dz * dz))); // log2e*d
            float d = LN2 * ds;                                        // true distance
            float pi = __builtin_amdgcn_exp2f(ds + u2 + (&vv.x)[c]);   // exp(d+u+v)
            (&dv.x)[c] = d;
            (&pv.x)[c] = pi;
            acc = fmaf(pi, d, acc);
        }
        outD[base4 + t] = dv;
        outPi[base4 + t] = pv;
    }
    #pragma unroll
    for (int off = 32; off; off >>= 1) acc += __shfl_xor(acc, off);
    __shared__ float sred[4];
    if ((threadIdx.x & 63) == 0) sred[threadIdx.x >> 6] = acc;
    __syncthreads();
    if (threadIdx.x == 0) rowsum[row] = sred[0] + sred[1] + sred[2] + sred[3];
}

__global__ __launch_bounds__(256) void sk_cost(const float* __restrict__ rowsum,
                                               float* __restrict__ cost)
{
    const int b = blockIdx.x;
    float acc = 0.f;
    for (int i = threadIdx.x; i < P; i += 256) acc += rowsum[b * P + i];
    #pragma unroll
    for (int off = 32; off; off >>= 1) acc += __shfl_xor(acc, off);
    __shared__ float sred[4];
    if ((threadIdx.x & 63) == 0) sred[threadIdx.x >> 6] = acc;
    __syncthreads();
    if (threadIdx.x == 0) cost[b] = sred[0] + sred[1] + sred[2] + sred[3];
}

extern "C" void kernel_launch(void* const* d_in, const int* in_sizes, int n_in,
                              void* d_out, int out_size, void* d_ws, size_t ws_size,
                              hipStream_t stream)
{
    const float* x = (const float*)d_in[0];
    const float* y = (const float*)d_in[1];

    float* out  = (float*)d_out;
    float* cost = out;                                 // [8]
    float* pi   = out + BATCH;                         // [8*2048*2048]
    float* Dm   = pi + (size_t)BATCH * P * P;          // [8*2048*2048]

    // E and E^T (fp16) live in the pi region during the loop: 67 MB + 67 MB
    // = exactly the 134 MB pi region. sk_final overwrites it afterwards.
    uint4* E  = (uint4*)pi;                            // [8*2048 rows][256 uint4]
    uint4* ET = E + (size_t)BATCH * P * (P / 8);

    float* u      = (float*)d_ws;                      // [16384] log2-space
    float* v      = u + BATCH * P;                     // [16384] log2-space
    float* rowsum = v + BATCH * P;                     // [16384]
    float4* xs    = (float4*)(rowsum + BATCH * P);     // [16384] float4
    float4* ys    = xs + BATCH * P;                    // [16384] float4
    int* cnt      = (int*)(ys + BATCH * P);            // [1600 arrivals + 1600 release]

    sk_prep<<<BATCH * P / 256, 256, 0, stream>>>(x, y, xs, ys, u, v, cnt);
    sk_einit<<<2 * BATCH * P, 256, 0, stream>>>(xs, ys, E, ET);

    {
        const uint4* E_c = E;
        const uint4* ET_c = ET;
        float* u_p = u;
        float* v_p = v;
        int* cnt_p = cnt;
        void* args[] = { (void*)&E_c, (void*)&ET_c, (void*)&u_p, (void*)&v_p, (void*)&cnt_p };
        hipError_t e = hipLaunchCooperativeKernel((const void*)sk_loop,
                                                  dim3(NWG), dim3(TPB),
                                                  args, 0, stream);
        if (e != hipSuccess) {
            // Fallback: plain launch. Grid == exact residency capacity
            // (512 wgs x 16 waves = 8192 waves = 256 CU x 32), so all wgs
            // are co-resident by construction.
            sk_loop<<<dim3(NWG), dim3(TPB), 0, stream>>>(E_c, ET_c, u_p, v_p, cnt_p);
        }
    }

    sk_final<<<BATCH * P, 256, 0, stream>>>(xs, ys, u, v,
                                            (float4*)pi, (float4*)Dm, rowsum);
    sk_cost<<<BATCH, 256, 0, stream>>>(rowsum, cost);
}

// Round 16
// 2426.351 us; speedup vs baseline: 1.6679x; 1.6679x over previous
//
#include <hip/hip_runtime.h>
#include <cmath>

// Sinkhorn distance, B=8, P1=P2=2048, dim=3, EPS=1, MAX_ITER=100, THRESH=1e-9
// Outputs (flat, in return order): cost[8], pi[8*2048*2048], D[8*2048*2048]
//
// Identities / hard-won rules:
//  - log2 domain everywhere; coords pre-scaled by log2(e); duals log2-space;
//    weights log2(1/2048) = -11.  u'_i = -11 - log2( sum_j exp2(v'_j - d'_ij) )
//  - THRESH=1e-9 < f32 ulp => reference stops only at a bitwise fixed point;
//    R8 measured none in 100 iters => run exactly 100.
//  - RECOMPUTE beats memoized E: R15's fp16-E GEMV streamed 33 MB/phase from
//    HBM (not MALL-resident) -> 19us/phase, worse than 13.2 recompute.
//  - Cross-wg dual exchange: 32-BIT agent-scope RELAXED atomics only
//    (64-bit atomic loads lower to RMW -> 10 GB HBM, R9). NO fences (R6).
//  - Barrier: arrival fetch_add on write-only counter; 64th arriver stores a
//    separate once-written release flag everyone polls (one hot line/batch).
//    (R11's per-wg padded epoch array = 70 GB coherence traffic.)
//  - Register budget 64 VGPRs (launch_bounds 1024,8): W[] exp2'd at preload,
//    8-chunk segments only (R12: bigger live arrays spill -> 59 GB HBM).
//  - Lean tail (this round): each wave owns 2 rows x FULL j-range -> no
//    cross-wave combine, no wpart, one syncthreads less; every wave stores
//    its own 2 duals + per-wave vmcnt drain before the block barrier.
//  - Final D/pi/cost in a separate 16384-block kernel (R13: folding +290us).

constexpr int BATCH = 8;
constexpr int P = 2048;
constexpr int MAX_ITER = 100;
constexpr int WGS_PER_BATCH = 64;            // 32 rows each
constexpr int NWG = BATCH * WGS_PER_BATCH;   // 512 blocks
constexpr int TPB = 1024;                    // 16 waves
constexpr int NPHASE = 2 * MAX_ITER;

#define LOG2E 1.44269504088896340736f
#define LN2   0.69314718055994530942f

typedef __attribute__((ext_vector_type(2))) float v2f;

static __device__ __forceinline__ v2f mkv2(float a, float b) { v2f r; r.x = a; r.y = b; return r; }

// Pack pre-scaled coords into float4; init duals; zero counters + release flags.
__global__ __launch_bounds__(256) void sk_prep(const float* __restrict__ x,
                                               const float* __restrict__ y,
                                               float4* __restrict__ xs,
                                               float4* __restrict__ ys,
                                               float* __restrict__ u,
                                               float* __restrict__ v,
                                               int* __restrict__ cnt)
{
    int idx = blockIdx.x * 256 + threadIdx.x;   // 0 .. BATCH*P-1
    u[idx] = 0.0f;     // log2-space u0 = 0
    v[idx] = -11.0f;   // log2-space v0 = log2(1/2048)
    xs[idx] = make_float4(LOG2E * x[3*idx], LOG2E * x[3*idx+1], LOG2E * x[3*idx+2], 0.f);
    ys[idx] = make_float4(LOG2E * y[3*idx], LOG2E * y[3*idx+1], LOG2E * y[3*idx+2], 0.f);
    if (idx < 2 * BATCH * NPHASE) cnt[idx] = 0;   // arrivals + release flags
}

// The whole Sinkhorn loop in one kernel.
// Block: 1024 thr = 16 waves; each wave owns 2 rows x full j-range.
__global__ __launch_bounds__(TPB, 8) void sk_loop(const float4* __restrict__ xs,
                                                  const float4* __restrict__ ys,
                                                  float* u,
                                                  float* v,
                                                  int* cnt)
{
    __shared__ v2f shx[2][P/2], shy[2][P/2], shz[2][P/2];  // [side][j/2], 48 KiB

    const int b = blockIdx.x & 7;                   // batch (XCD-local heuristic)
    const int wg = blockIdx.x >> 3;                 // 0..63 within batch
    const int wgrow = wg << 5;                      // this wg's 32-row base
    const int w = threadIdx.x >> 6;
    const int lane = threadIdx.x & 63;
    const int i0 = wgrow + 2 * w;                   // this wave's 2 rows

    const float4* xb = xs + (size_t)b * P;
    const float4* yb = ys + (size_t)b * P;
    float* ub = u + (size_t)b * P;
    float* vb = v + (size_t)b * P;
    int* bar = cnt + b * NPHASE;                    // arrival counters (write-only)
    int* rel = cnt + BATCH * NPHASE + b * NPHASE;   // release flags (single writer)

    // Stage BOTH coordinate sides into LDS once (read-only thereafter).
    {
        const int t = threadIdx.x;                  // 0..1023 == P/2 entries
        float4 a0 = xb[2*t], a1 = xb[2*t + 1];
        shx[0][t] = mkv2(a0.x, a1.x);
        shy[0][t] = mkv2(a0.y, a1.y);
        shz[0][t] = mkv2(a0.z, a1.z);
        float4 c0 = yb[2*t], c1 = yb[2*t + 1];
        shx[1][t] = mkv2(c0.x, c1.x);
        shy[1][t] = mkv2(c0.y, c1.y);
        shz[1][t] = mkv2(c0.z, c1.z);
    }
    __syncthreads();

    #pragma unroll 1
    for (int it = 0; it < MAX_ITER; ++it) {
        #pragma unroll 1
        for (int ph = 0; ph < 2; ++ph) {
            float* dr = ph ? ub : vb;               // duals being reduced over
            float* dw = ph ? vb : ub;               // duals being written
            const int side = 1 - ph;                // LDS coord side reduced over

            // Own 2 rows' coords from LDS (array index == ph). i0 even.
            float cx0, cy0, cz0, cx1, cy1, cz1;
            {
                const int e0 = i0 >> 1;
                v2f xa = shx[ph][e0], ya = shy[ph][e0], za = shz[ph][e0];
                cx0 = xa.x; cx1 = xa.y;
                cy0 = ya.x; cy1 = ya.y;
                cz0 = za.x; cz1 = za.y;
            }

            v2f acc0 = mkv2(0.f, 0.f), acc1 = mkv2(0.f, 0.f);

            const v2f* sx = shx[side];
            const v2f* sy = shy[side];
            const v2f* sz = shz[side];

            // Two half-segments; per segment preload 8 dual chunks (16 VGPRs),
            // exp2 immediately (no spill), then 8 compute units.
            #pragma unroll 1
            for (int hseg = 0; hseg < 2; ++hseg) {
                const int tbase = (hseg << 9) + lane;   // v2f index

                v2f W[8];
                #pragma unroll
                for (int k = 0; k < 8; ++k) {
                    const int t = tbase + (k << 6);
                    float d0 = __hip_atomic_load(&dr[2*t],     __ATOMIC_RELAXED, __HIP_MEMORY_SCOPE_AGENT);
                    float d1 = __hip_atomic_load(&dr[2*t + 1], __ATOMIC_RELAXED, __HIP_MEMORY_SCOPE_AGENT);
                    W[k] = mkv2(d0, d1);
                }
                #pragma unroll
                for (int k = 0; k < 8; ++k) {
                    W[k].x = __builtin_amdgcn_exp2f(W[k].x);
                    W[k].y = __builtin_amdgcn_exp2f(W[k].y);
                }

                #pragma unroll 4
                for (int k = 0; k < 8; ++k) {
                    const int t = tbase + (k << 6);
                    v2f X = sx[t];
                    v2f Y = sy[t];
                    v2f Z = sz[t];
                    {
                        v2f dx = X - cx0;
                        v2f dy = Y - cy0;
                        v2f dz = Z - cz0;
                        v2f r2 = dx*dx + dy*dy + dz*dz;
                        v2f e;
                        e.x = __builtin_amdgcn_exp2f(-__builtin_amdgcn_sqrtf(r2.x));
                        e.y = __builtin_amdgcn_exp2f(-__builtin_amdgcn_sqrtf(r2.y));
                        acc0 += W[k] * e;
                    }
                    {
                        v2f dx = X - cx1;
                        v2f dy = Y - cy1;
                        v2f dz = Z - cz1;
                        v2f r2 = dx*dx + dy*dy + dz*dz;
                        v2f e;
                        e.x = __builtin_amdgcn_exp2f(-__builtin_amdgcn_sqrtf(r2.x));
                        e.y = __builtin_amdgcn_exp2f(-__builtin_amdgcn_sqrtf(r2.y));
                        acc1 += W[k] * e;
                    }
                }
            }

            // Per-wave reduce + per-wave dual stores (lane 0), no cross-wave combine.
            float s0 = acc0.x + acc0.y;
            float s1 = acc1.x + acc1.y;
            #pragma unroll
            for (int off = 32; off; off >>= 1) {
                s0 += __shfl_xor(s0, off);
                s1 += __shfl_xor(s1, off);
            }
            if (lane == 0) {
                __hip_atomic_store(&dw[i0],     -11.0f - __builtin_amdgcn_logf(s0),
                                   __ATOMIC_RELAXED, __HIP_MEMORY_SCOPE_AGENT);
                __hip_atomic_store(&dw[i0 + 1], -11.0f - __builtin_amdgcn_logf(s1),
                                   __ATOMIC_RELAXED, __HIP_MEMORY_SCOPE_AGENT);
            }
            // Per-wave drain: this wave's dual stores acked at IF before barrier.
            asm volatile("s_waitcnt vmcnt(0)" ::: "memory");
            __syncthreads();

            // Per-batch barrier, arrival/release split. Skip after last phase
            // (kernel boundary syncs before sk_final).
            if (it == MAX_ITER - 1 && ph == 1) continue;
            if (threadIdx.x == 0) {
                const int idx = it * 2 + ph;
                int old = __hip_atomic_fetch_add(&bar[idx], 1, __ATOMIC_RELAXED,
                                                 __HIP_MEMORY_SCOPE_AGENT);
                if (old == WGS_PER_BATCH - 1) {
                    __hip_atomic_store(&rel[idx], 1, __ATOMIC_RELAXED,
                                       __HIP_MEMORY_SCOPE_AGENT);
                } else {
                    while (__hip_atomic_load(&rel[idx], __ATOMIC_RELAXED,
                                             __HIP_MEMORY_SCOPE_AGENT) == 0)
                        __builtin_amdgcn_s_sleep(1);
                }
            }
            __syncthreads();
        }
    }
}

// Final: D, pi = exp(D + u + v) (faithful to reference's +D sign), rowsum of pi*D.
// One block per output row; float4 loads/stores (write-bound: 268 MB).
__global__ __launch_bounds__(256) void sk_final(const float4* __restrict__ xs,
                                                const float4* __restrict__ ys,
                                                const float* __restrict__ u,
                                                const float* __restrict__ v,
                                                float4* __restrict__ outPi,
                                                float4* __restrict__ outD,
                                                float* __restrict__ rowsum)
{
    const int row = blockIdx.x;        // b*P + i
    const int b = row >> 11;

    const float4 a = xs[row];          // scaled x_i
    const float u2 = u[row];           // log2-space u_i
    const float4* vb4 = (const float4*)(v + (size_t)b * P);
    const float4* yb = ys + (size_t)b * P;
    const size_t base4 = (size_t)row * (P / 4);

    float acc = 0.f;
    for (int t = threadIdx.x; t < P / 4; t += 256) {
        float4 dv, pv;
        float4 vv = vb4[t];
        #pragma unroll
        for (int c = 0; c < 4; ++c) {
            int j = 4 * t + c;
            float4 q = yb[j];
            float dx = a.x - q.x;
            float dy = a.y - q.y;
            float dz = a.z - q.z;
            float ds = __builtin_amdgcn_sqrtf(fmaf(dx, dx, fmaf(dy, dy, dz * dz))); // log2e*d
            float d = LN2 * ds;                                        // true distance
            float pi = __builtin_amdgcn_exp2f(ds + u2 + (&vv.x)[c]);   // exp(d+u+v)
            (&dv.x)[c] = d;
            (&pv.x)[c] = pi;
            acc = fmaf(pi, d, acc);
        }
        outD[base4 + t] = dv;
        outPi[base4 + t] = pv;
    }
    #pragma unroll
    for (int off = 32; off; off >>= 1) acc += __shfl_xor(acc, off);
    __shared__ float sred[4];
    if ((threadIdx.x & 63) == 0) sred[threadIdx.x >> 6] = acc;
    __syncthreads();
    if (threadIdx.x == 0) rowsum[row] = sred[0] + sred[1] + sred[2] + sred[3];
}

__global__ __launch_bounds__(256) void sk_cost(const float* __restrict__ rowsum,
                                               float* __restrict__ cost)
{
    const int b = blockIdx.x;
    float acc = 0.f;
    for (int i = threadIdx.x; i < P; i += 256) acc += rowsum[b * P + i];
    #pragma unroll
    for (int off = 32; off; off >>= 1) acc += __shfl_xor(acc, off);
    __shared__ float sred[4];
    if ((threadIdx.x & 63) == 0) sred[threadIdx.x >> 6] = acc;
    __syncthreads();
    if (threadIdx.x == 0) cost[b] = sred[0] + sred[1] + sred[2] + sred[3];
}

extern "C" void kernel_launch(void* const* d_in, const int* in_sizes, int n_in,
                              void* d_out, int out_size, void* d_ws, size_t ws_size,
                              hipStream_t stream)
{
    const float* x = (const float*)d_in[0];
    const float* y = (const float*)d_in[1];

    float* out  = (float*)d_out;
    float* cost = out;                                 // [8]
    float* pi   = out + BATCH;                         // [8*2048*2048]
    float* Dm   = pi + (size_t)BATCH * P * P;          // [8*2048*2048]

    float* u      = (float*)d_ws;                      // [16384] log2-space
    float* v      = u + BATCH * P;                     // [16384] log2-space
    float* rowsum = v + BATCH * P;                     // [16384]
    float4* xs    = (float4*)(rowsum + BATCH * P);     // [16384] float4
    float4* ys    = xs + BATCH * P;                    // [16384] float4
    int* cnt      = (int*)(ys + BATCH * P);            // [1600 arrivals + 1600 release]

    sk_prep<<<BATCH * P / 256, 256, 0, stream>>>(x, y, xs, ys, u, v, cnt);

    {
        const float4* xs_c = xs;
        const float4* ys_c = ys;
        float* u_p = u;
        float* v_p = v;
        int* cnt_p = cnt;
        void* args[] = { (void*)&xs_c, (void*)&ys_c, (void*)&u_p, (void*)&v_p, (void*)&cnt_p };
        hipError_t e = hipLaunchCooperativeKernel((const void*)sk_loop,
                                                  dim3(NWG), dim3(TPB),
                                                  args, 0, stream);
        if (e != hipSuccess) {
            // Fallback: plain launch. Grid == exact residency capacity
            // (512 wgs x 16 waves = 8192 waves = 256 CU x 32; LDS 48KB -> 2/CU),
            // so all wgs are co-resident by construction.
            sk_loop<<<dim3(NWG), dim3(TPB), 0, stream>>>(xs_c, ys_c, u_p, v_p, cnt_p);
        }
    }

    sk_final<<<BATCH * P, 256, 0, stream>>>(xs, ys, u, v,
                                            (float4*)pi, (float4*)Dm, rowsum);
    sk_cost<<<BATCH, 256, 0, stream>>>(rowsum, cost);
}